// Round 16
// baseline (49.483 us; speedup 1.0000x reference)
//
#include <hip/hip_runtime.h>

#define KIN 1024

__device__ __forceinline__ float4 f4add(float4 a, float4 b) {
    return make_float4(a.x + b.x, a.y + b.y, a.z + b.z, a.w + b.w);
}
__device__ __forceinline__ unsigned short f2bf(float f) {   // RNE bf16
    unsigned int u = __float_as_uint(f);
    u += 0x7FFFu + ((u >> 16) & 1u);
    return (unsigned short)(u >> 16);
}
__device__ __forceinline__ float bf2f(unsigned int u) {     // low 16 bits
    return __uint_as_float((u & 0xFFFFu) << 16);
}
__device__ __forceinline__ unsigned int pack2(float a, float b) {
    return (unsigned int)f2bf(a) | ((unsigned int)f2bf(b) << 16);
}

typedef __attribute__((ext_vector_type(8))) short bf16x8;
typedef __attribute__((ext_vector_type(4))) float f32x4;

// ---------------------------------------------------------------------------
// K1: blocks [0,16): convert Wv/Wh (64d x 256k fp32) -> bf16 row-major.
//     blocks [16,4368): single-pass col/row reduction per (img, pr); img
//       0..255 = x[bc] -> bf16 cs/rs; img 256..271 = pe[c] -> fp32 pe buffers.
//     blocks [4368,5136): convert Vw/Hw (fp32, k-major) -> bf16.
// ---------------------------------------------------------------------------
__global__ __launch_bounds__(256) void k1_fused(
    const float* __restrict__ x, const float* __restrict__ pe,
    const float* __restrict__ Wv, const float* __restrict__ Wh,
    const float* __restrict__ Vw, const float* __restrict__ Hw,
    unsigned short* __restrict__ wv_bf, unsigned short* __restrict__ wh_bf,
    unsigned short* __restrict__ Vw_bf, unsigned short* __restrict__ Hw_bf,
    unsigned short* __restrict__ cs_bf, unsigned short* __restrict__ rs_bf,
    float* __restrict__ pe_cs, float* __restrict__ pe_rs)
{
    const int blk = blockIdx.x, t = threadIdx.x;

    if (blk < 16) {                                  // --- Wv/Wh -> bf16 ---
        const int idx = blk * 256 + t;               // 0..4095
        const int mat = idx >> 11, rem = idx & 2047;
        const int d = rem >> 5, c8 = (rem & 31) * 8;
        const float* W = mat ? Wh : Wv;
        float4 v0 = *(const float4*)(W + d * 256 + c8);
        float4 v1 = *(const float4*)(W + d * 256 + c8 + 4);
        uint4 o;
        o.x = pack2(v0.x, v0.y); o.y = pack2(v0.z, v0.w);
        o.z = pack2(v1.x, v1.y); o.w = pack2(v1.z, v1.w);
        *(uint4*)((mat ? wh_bf : wv_bf) + d * 256 + c8) = o;
        return;
    }

    if (blk >= 4368) {                               // --- Vw/Hw -> bf16 ---
        const int idx = blk - 4368;                  // 0..767
        #pragma unroll
        for (int rr = 0; rr < 2; ++rr) {
            const int row = 2 * idx + rr;            // 0..1535 (Vw then Hw)
            const float4* src = (const float4*)((row < 768)
                ? (Vw + (size_t)row * 1024)
                : (Hw + (size_t)(row - 768) * 1024));
            unsigned short* dst = ((row < 768) ? Vw_bf + (size_t)row * 1024
                                               : Hw_bf + (size_t)(row - 768) * 1024);
            float4 v = src[t];
            ushort4 o = make_ushort4(f2bf(v.x), f2bf(v.y), f2bf(v.z), f2bf(v.w));
            ((ushort4*)dst)[t] = o;
        }
        return;
    }

    __shared__ float srow[16][264];   // 16 rows x 256 cols (+8 pad)
    __shared__ float cpart[4][256];

    const int b2 = blk - 16;                         // 0..4351
    const int img = b2 >> 4, pr = b2 & 15;
    const bool isX = img < 256;
    const float* ib = isX ? (x + (size_t)img * 65536)
                          : (pe + (size_t)(img - 256) * 65536);
    const int w = t >> 6, l = t & 63;

    float4 v[4];
    const float* base = ib + (size_t)(pr + 64 * w) * 256 + 4 * l;
    #pragma unroll
    for (int j = 0; j < 4; ++j)
        v[j] = *(const float4*)(base + j * 4096);

    *(float4*)&cpart[w][4 * l] = f4add(f4add(v[0], v[1]), f4add(v[2], v[3]));

    #pragma unroll
    for (int j = 0; j < 4; ++j)
        *(float4*)&srow[4 * w + j][4 * l] = v[j];
    __syncthreads();

    {   // rowsum: thread (lr, pc) sums 16 strided elements of one row
        const int lr = t >> 4, pc = t & 15;
        float s = 0.f;
        #pragma unroll
        for (int i = 0; i < 16; ++i) s += srow[lr][pc + 16 * i];
        const int grow = pr + 16 * lr;
        if (isX) rs_bf[(size_t)img * 4096 + grow * 16 + pc] = f2bf(s);
        else     pe_rs[(size_t)(img - 256) * 4096 + grow * 16 + pc] = s;
    }
    {   // colsum combine
        const float s = cpart[0][t] + cpart[1][t] + cpart[2][t] + cpart[3][t];
        if (isX) cs_bf[(size_t)img * 4096 + pr * 256 + t] = f2bf(s);
        else     pe_cs[(size_t)(img - 256) * 4096 + pr * 256 + t] = s;
    }
}

// ---------------------------------------------------------------------------
// K1c (MFMA): per (seg, bct, mat) block: out[bc][d] = sum_{k<256} A[bc][k]*W[d][k]
//   V: A[bc][k] = (cs_bf+pe_cs)[bc][(k>>4)*256 + seg*16 + (k&15)]
//   H: A[bc][k] = (rs_bf+pe_rs)[bc][seg*256 + k]
// A staged bf16 + fp32 pe fold. W pre-converted bf16. Epilogue adds 16*bias,
// stores bf16 vcomp/hcomp. grid (16 seg, 4 bct, 2 mat), 256 threads.
// ---------------------------------------------------------------------------
__global__ __launch_bounds__(256) void k1c_mfma(
    const unsigned short* __restrict__ cs_bf, const unsigned short* __restrict__ rs_bf,
    const float* __restrict__ pe_cs, const float* __restrict__ pe_rs,
    const unsigned short* __restrict__ wv_bf, const unsigned short* __restrict__ wh_bf,
    const float* __restrict__ bv, const float* __restrict__ bh,
    unsigned short* __restrict__ vcomp_bf, unsigned short* __restrict__ hcomp_bf)
{
    __shared__ unsigned short As[64][264];   // 64 bc x 256 k (+8 pad)
    __shared__ unsigned short Bs[64][264];   // 64 d  x 256 k (+8 pad)

    const int seg = blockIdx.x;              // 0..15
    const int bc0 = blockIdx.y * 64;         // 0..192
    const int mat = blockIdx.z;
    const unsigned short* S = mat ? rs_bf : cs_bf;
    const float*         PE = mat ? pe_rs : pe_cs;
    const unsigned short* Wbf = mat ? wh_bf : wv_bf;
    const float* bb = mat ? bh : bv;
    unsigned short* dst = mat ? hcomp_bf : vcomp_bf;

    const int t = threadIdx.x, w = t >> 6, l = t & 63;

    {   // stage A: row = t>>2, k-quarter = (t&3)*64; bf16 + fp32 pe fold
        const int row = t >> 2, kq0 = (t & 3) * 64;
        const unsigned short* bx = S + (size_t)(bc0 + row) * 4096;
        const float* bp = PE + (size_t)((bc0 + row) & 15) * 4096;
        #pragma unroll
        for (int f = 0; f < 8; ++f) {
            const int k2 = kq0 + f * 8;
            const int off = mat ? (seg * 256 + k2)
                                : ((k2 >> 4) * 256 + seg * 16 + (k2 & 15));
            uint4 va = *(const uint4*)(bx + off);
            float4 p0 = *(const float4*)(bp + off);
            float4 p1 = *(const float4*)(bp + off + 4);
            uint4 o;
            o.x = pack2(bf2f(va.x) + p0.x, bf2f(va.x >> 16) + p0.y);
            o.y = pack2(bf2f(va.y) + p0.z, bf2f(va.y >> 16) + p0.w);
            o.z = pack2(bf2f(va.z) + p1.x, bf2f(va.z >> 16) + p1.y);
            o.w = pack2(bf2f(va.w) + p1.z, bf2f(va.w >> 16) + p1.w);
            *(uint4*)&As[row][k2] = o;
        }
    }
    // stage B: plain bf16 copy (2048 uint4)
    #pragma unroll
    for (int j = 0; j < 8; ++j) {
        const int idx = t + j * 256;
        const int d = idx >> 5, c8 = (idx & 31) * 8;
        *(uint4*)&Bs[d][c8] = *(const uint4*)(Wbf + d * 256 + c8);
    }
    __syncthreads();

    f32x4 acc[4];
    #pragma unroll
    for (int nf = 0; nf < 4; ++nf) acc[nf] = (f32x4)(0.f);

    #pragma unroll
    for (int kst = 0; kst < 8; ++kst) {
        const int kl = kst * 32 + (l >> 4) * 8;
        bf16x8 a = *(const bf16x8*)&As[w * 16 + (l & 15)][kl];
        #pragma unroll
        for (int nf = 0; nf < 4; ++nf) {
            bf16x8 b = *(const bf16x8*)&Bs[nf * 16 + (l & 15)][kl];
            acc[nf] = __builtin_amdgcn_mfma_f32_16x16x32_bf16(a, b, acc[nf], 0, 0, 0);
        }
    }

    #pragma unroll
    for (int nf = 0; nf < 4; ++nf) {
        const int d = nf * 16 + (l & 15);
        const float bias = 16.f * bb[d];
        #pragma unroll
        for (int q = 0; q < 4; ++q) {
            const int bc = bc0 + w * 16 + (l >> 4) * 4 + q;
            dst[(size_t)bc * KIN + seg * 64 + d] = f2bf(acc[nf][q] + bias);
        }
    }
}

// ---------------------------------------------------------------------------
// K2 (MFMA bf16): P[ks][bc][r][n] = sum_k A[bc][k]*B[rn][k], A=vcomp_bf,
// B=W_bf, both k-major. Block tile 64bc x 64rn; R10-proven.
// grid (12 rn-tiles, 4 bct * KS, 2 mats).
// ---------------------------------------------------------------------------
__global__ __launch_bounds__(256) void k2_mfma(
    const unsigned short* __restrict__ vcomp_bf,
    const unsigned short* __restrict__ hcomp_bf,
    const unsigned short* __restrict__ Vw_bf,
    const unsigned short* __restrict__ Hw_bf,
    float* __restrict__ Vp, float* __restrict__ Hp, int KSplit, int KC)
{
    __shared__ unsigned short As[64][136];   // 64 bc x 128 k (+8 pad)
    __shared__ unsigned short Bs[64][136];   // 64 rn x 128 k (+8 pad)

    const int mat = blockIdx.z;
    const unsigned short* A = mat ? hcomp_bf : vcomp_bf;
    const unsigned short* B = mat ? Hw_bf : Vw_bf;
    float*                P = mat ? Hp : Vp;

    const int rn0 = blockIdx.x * 64;                  // 0..704
    const int bct = blockIdx.y / KSplit, ks = blockIdx.y % KSplit;
    const int bc0 = bct * 64;
    const int t = threadIdx.x, w = t >> 6, l = t & 63;

    f32x4 acc[4];
    #pragma unroll
    for (int nf = 0; nf < 4; ++nf) acc[nf] = (f32x4)(0.f);

    const int nch = KC >> 7;                          // chunks of 128 k
    for (int ch = 0; ch < nch; ++ch) {
        const int k0 = ks * KC + ch * 128;
        #pragma unroll
        for (int j = 0; j < 4; ++j) {                 // stage A and B chunks
            const int idx = t + j * 256;              // 0..1023
            const int row = idx >> 4, c16 = idx & 15;
            uint4 va = *(const uint4*)(A + (size_t)(bc0 + row) * KIN + k0 + c16 * 8);
            *(uint4*)&As[row][c16 * 8] = va;
            uint4 vb = *(const uint4*)(B + (size_t)(rn0 + row) * KIN + k0 + c16 * 8);
            *(uint4*)&Bs[row][c16 * 8] = vb;
        }
        __syncthreads();

        #pragma unroll
        for (int kst = 0; kst < 4; ++kst) {           // 4 x K=32 steps
            const int kl = kst * 32 + (l >> 4) * 8;
            bf16x8 a = *(const bf16x8*)&As[w * 16 + (l & 15)][kl];
            #pragma unroll
            for (int nf = 0; nf < 4; ++nf) {
                bf16x8 b = *(const bf16x8*)&Bs[nf * 16 + (l & 15)][kl];
                acc[nf] = __builtin_amdgcn_mfma_f32_16x16x32_bf16(a, b, acc[nf], 0, 0, 0);
            }
        }
        __syncthreads();
    }

    // epilogue: store fp32 partials
    const int r = rn0 >> 8;
    const int nbase = rn0 & 255;
    #pragma unroll
    for (int nf = 0; nf < 4; ++nf) {
        const int n = nbase + nf * 16 + (l & 15);
        #pragma unroll
        for (int q = 0; q < 4; ++q) {
            const int m = (l >> 4) * 4 + q;
            const int bc = bc0 + w * 16 + m;
            P[(((size_t)ks * 256 + bc) * 3 + r) * 256 + n] = acc[nf][q];
        }
    }
}

// ---------------------------------------------------------------------------
// K3: reduce split-K partials (+bias), out = V H^T (rank 3). Write-bound.
// (R6/R9/R10-proven scalar-store version, grid (2, 256).)
// ---------------------------------------------------------------------------
__global__ __launch_bounds__(256) void k3_outer(
    const float* __restrict__ Vp, const float* __restrict__ Hp,
    const float* __restrict__ Vb, const float* __restrict__ Hb,
    float* __restrict__ out, int KSplit)
{
    __shared__ float sh[3][256];
    __shared__ float sv[3][128];

    const int bc = blockIdx.y, nt = blockIdx.x, t = threadIdx.x;

    #pragma unroll
    for (int r = 0; r < 3; ++r) {
        float a = Hb[r * 256 + t];
        for (int ks = 0; ks < KSplit; ++ks)
            a += Hp[(((size_t)ks * 256 + bc) * 3 + r) * 256 + t];
        sh[r][t] = a;
    }
    for (int idx = t; idx < 384; idx += 256) {
        int r = idx >> 7, nn = idx & 127;
        float a = Vb[r * 256 + nt * 128 + nn];
        for (int ks = 0; ks < KSplit; ++ks)
            a += Vp[(((size_t)ks * 256 + bc) * 3 + r) * 256 + nt * 128 + nn];
        sv[r][nn] = a;
    }
    __syncthreads();

    const float h0 = sh[0][t], h1 = sh[1][t], h2 = sh[2][t];
    float* ob = out + ((size_t)bc * 256 + nt * 128) * 256;
    #pragma unroll 4
    for (int nn = 0; nn < 128; ++nn)
        ob[nn * 256 + t] = sv[0][nn] * h0 + sv[1][nn] * h1 + sv[2][nn] * h2;
}

extern "C" void kernel_launch(void* const* d_in, const int* in_sizes, int n_in,
                              void* d_out, int out_size, void* d_ws, size_t ws_size,
                              hipStream_t stream)
{
    const float* x  = (const float*)d_in[0];
    const float* pe = (const float*)d_in[1];
    const float* Wv = (const float*)d_in[2];
    const float* bv = (const float*)d_in[3];
    const float* Wh = (const float*)d_in[4];
    const float* bh = (const float*)d_in[5];
    const float* Vw = (const float*)d_in[6];
    const float* Vb = (const float*)d_in[7];
    const float* Hw = (const float*)d_in[8];
    const float* Hb = (const float*)d_in[9];
    float* out = (float*)d_out;

    // ws layout (float-slot offsets)
    float* ws = (float*)d_ws;
    unsigned short* wv_bf = (unsigned short*)ws;                 // 8192 fl
    unsigned short* wh_bf = (unsigned short*)(ws + 8192);        // 8192 fl
    unsigned short* cs_bf = (unsigned short*)(ws + 16384);       // 524288 fl
    unsigned short* rs_bf = (unsigned short*)(ws + 540672);      // 524288 fl
    float* pe_cs = ws + 1064960;                                 // 65536
    float* pe_rs = ws + 1130496;                                 // 65536
    unsigned short* vcomp_bf = (unsigned short*)(ws + 1196032);  // 131072 fl
    unsigned short* hcomp_bf = (unsigned short*)(ws + 1327104);  // 131072 fl
    unsigned short* Vw_bf    = (unsigned short*)(ws + 1458176);  // 393216 fl
    unsigned short* Hw_bf    = (unsigned short*)(ws + 1851392);  // 393216 fl
    float* rest = ws + 2244608;                                  // split-K partials

    const int KS = 1;                                            // KS 2->1
    const int KC = KIN / KS;

    float* Vp = rest;
    float* Hp = rest + (size_t)KS * 196608;

    k1_fused<<<16 + 4352 + 768, 256, 0, stream>>>(
        x, pe, Wv, Wh, Vw, Hw, wv_bf, wh_bf, Vw_bf, Hw_bf,
        cs_bf, rs_bf, pe_cs, pe_rs);
    k1c_mfma<<<dim3(16, 4, 2), 256, 0, stream>>>(
        cs_bf, rs_bf, pe_cs, pe_rs, wv_bf, wh_bf, bv, bh, vcomp_bf, hcomp_bf);
    k2_mfma<<<dim3(12, 4 * KS, 2), 256, 0, stream>>>(
        vcomp_bf, hcomp_bf, Vw_bf, Hw_bf, Vp, Hp, KS, KC);
    k3_outer<<<dim3(2, 256), 256, 0, stream>>>(Vp, Hp, Vb, Hb, out, KS);
}

// Round 17
// 49.164 us; speedup vs baseline: 1.0065x; 1.0065x over previous
//
#include <hip/hip_runtime.h>

#define KIN 1024

__device__ __forceinline__ float4 f4add(float4 a, float4 b) {
    return make_float4(a.x + b.x, a.y + b.y, a.z + b.z, a.w + b.w);
}
__device__ __forceinline__ unsigned short f2bf(float f) {   // RNE bf16
    unsigned int u = __float_as_uint(f);
    u += 0x7FFFu + ((u >> 16) & 1u);
    return (unsigned short)(u >> 16);
}
__device__ __forceinline__ float bf2f(unsigned int u) {     // low 16 bits
    return __uint_as_float((u & 0xFFFFu) << 16);
}
__device__ __forceinline__ unsigned int pack2(float a, float b) {
    return (unsigned int)f2bf(a) | ((unsigned int)f2bf(b) << 16);
}

typedef __attribute__((ext_vector_type(8))) short bf16x8;
typedef __attribute__((ext_vector_type(4))) float f32x4;

// ---------------------------------------------------------------------------
// K1: blocks [0,16): convert Wv/Wh (64d x 256k fp32) -> bf16 row-major.
//     blocks [16,4368): single-pass col/row reduction per (img, pr); img
//       0..255 = x[bc] -> bf16 cs/rs; img 256..271 = pe[c] -> fp32 pe buffers.
//     blocks [4368,5136): convert Vw/Hw (fp32, k-major) -> bf16.
// ---------------------------------------------------------------------------
__global__ __launch_bounds__(256) void k1_fused(
    const float* __restrict__ x, const float* __restrict__ pe,
    const float* __restrict__ Wv, const float* __restrict__ Wh,
    const float* __restrict__ Vw, const float* __restrict__ Hw,
    unsigned short* __restrict__ wv_bf, unsigned short* __restrict__ wh_bf,
    unsigned short* __restrict__ Vw_bf, unsigned short* __restrict__ Hw_bf,
    unsigned short* __restrict__ cs_bf, unsigned short* __restrict__ rs_bf,
    float* __restrict__ pe_cs, float* __restrict__ pe_rs)
{
    const int blk = blockIdx.x, t = threadIdx.x;

    if (blk < 16) {                                  // --- Wv/Wh -> bf16 ---
        const int idx = blk * 256 + t;               // 0..4095
        const int mat = idx >> 11, rem = idx & 2047;
        const int d = rem >> 5, c8 = (rem & 31) * 8;
        const float* W = mat ? Wh : Wv;
        float4 v0 = *(const float4*)(W + d * 256 + c8);
        float4 v1 = *(const float4*)(W + d * 256 + c8 + 4);
        uint4 o;
        o.x = pack2(v0.x, v0.y); o.y = pack2(v0.z, v0.w);
        o.z = pack2(v1.x, v1.y); o.w = pack2(v1.z, v1.w);
        *(uint4*)((mat ? wh_bf : wv_bf) + d * 256 + c8) = o;
        return;
    }

    if (blk >= 4368) {                               // --- Vw/Hw -> bf16 ---
        const int idx = blk - 4368;                  // 0..767
        #pragma unroll
        for (int rr = 0; rr < 2; ++rr) {
            const int row = 2 * idx + rr;            // 0..1535 (Vw then Hw)
            const float4* src = (const float4*)((row < 768)
                ? (Vw + (size_t)row * 1024)
                : (Hw + (size_t)(row - 768) * 1024));
            unsigned short* dst = ((row < 768) ? Vw_bf + (size_t)row * 1024
                                               : Hw_bf + (size_t)(row - 768) * 1024);
            float4 v = src[t];
            ushort4 o = make_ushort4(f2bf(v.x), f2bf(v.y), f2bf(v.z), f2bf(v.w));
            ((ushort4*)dst)[t] = o;
        }
        return;
    }

    __shared__ float srow[16][264];   // 16 rows x 256 cols (+8 pad)
    __shared__ float cpart[4][256];

    const int b2 = blk - 16;                         // 0..4351
    const int img = b2 >> 4, pr = b2 & 15;
    const bool isX = img < 256;
    const float* ib = isX ? (x + (size_t)img * 65536)
                          : (pe + (size_t)(img - 256) * 65536);
    const int w = t >> 6, l = t & 63;

    float4 v[4];
    const float* base = ib + (size_t)(pr + 64 * w) * 256 + 4 * l;
    #pragma unroll
    for (int j = 0; j < 4; ++j)
        v[j] = *(const float4*)(base + j * 4096);

    *(float4*)&cpart[w][4 * l] = f4add(f4add(v[0], v[1]), f4add(v[2], v[3]));

    #pragma unroll
    for (int j = 0; j < 4; ++j)
        *(float4*)&srow[4 * w + j][4 * l] = v[j];
    __syncthreads();

    {   // rowsum: thread (lr, pc) sums 16 strided elements of one row
        const int lr = t >> 4, pc = t & 15;
        float s = 0.f;
        #pragma unroll
        for (int i = 0; i < 16; ++i) s += srow[lr][pc + 16 * i];
        const int grow = pr + 16 * lr;
        if (isX) rs_bf[(size_t)img * 4096 + grow * 16 + pc] = f2bf(s);
        else     pe_rs[(size_t)(img - 256) * 4096 + grow * 16 + pc] = s;
    }
    {   // colsum combine
        const float s = cpart[0][t] + cpart[1][t] + cpart[2][t] + cpart[3][t];
        if (isX) cs_bf[(size_t)img * 4096 + pr * 256 + t] = f2bf(s);
        else     pe_cs[(size_t)(img - 256) * 4096 + pr * 256 + t] = s;
    }
}

// ---------------------------------------------------------------------------
// K1c (MFMA): per (seg, bct, mat) block: out[bc][d] = sum_{k<256} A[bc][k]*W[d][k]
//   V: A[bc][k] = (cs_bf+pe_cs)[bc][(k>>4)*256 + seg*16 + (k&15)]
//   H: A[bc][k] = (rs_bf+pe_rs)[bc][seg*256 + k]
// A staged bf16 + fp32 pe fold. W pre-converted bf16. Epilogue adds 16*bias,
// stores bf16 vcomp/hcomp. grid (16 seg, 4 bct, 2 mat), 256 threads.
// ---------------------------------------------------------------------------
__global__ __launch_bounds__(256) void k1c_mfma(
    const unsigned short* __restrict__ cs_bf, const unsigned short* __restrict__ rs_bf,
    const float* __restrict__ pe_cs, const float* __restrict__ pe_rs,
    const unsigned short* __restrict__ wv_bf, const unsigned short* __restrict__ wh_bf,
    const float* __restrict__ bv, const float* __restrict__ bh,
    unsigned short* __restrict__ vcomp_bf, unsigned short* __restrict__ hcomp_bf)
{
    __shared__ unsigned short As[64][264];   // 64 bc x 256 k (+8 pad)
    __shared__ unsigned short Bs[64][264];   // 64 d  x 256 k (+8 pad)

    const int seg = blockIdx.x;              // 0..15
    const int bc0 = blockIdx.y * 64;         // 0..192
    const int mat = blockIdx.z;
    const unsigned short* S = mat ? rs_bf : cs_bf;
    const float*         PE = mat ? pe_rs : pe_cs;
    const unsigned short* Wbf = mat ? wh_bf : wv_bf;
    const float* bb = mat ? bh : bv;
    unsigned short* dst = mat ? hcomp_bf : vcomp_bf;

    const int t = threadIdx.x, w = t >> 6, l = t & 63;

    {   // stage A: row = t>>2, k-quarter = (t&3)*64; bf16 + fp32 pe fold
        const int row = t >> 2, kq0 = (t & 3) * 64;
        const unsigned short* bx = S + (size_t)(bc0 + row) * 4096;
        const float* bp = PE + (size_t)((bc0 + row) & 15) * 4096;
        #pragma unroll
        for (int f = 0; f < 8; ++f) {
            const int k2 = kq0 + f * 8;
            const int off = mat ? (seg * 256 + k2)
                                : ((k2 >> 4) * 256 + seg * 16 + (k2 & 15));
            uint4 va = *(const uint4*)(bx + off);
            float4 p0 = *(const float4*)(bp + off);
            float4 p1 = *(const float4*)(bp + off + 4);
            uint4 o;
            o.x = pack2(bf2f(va.x) + p0.x, bf2f(va.x >> 16) + p0.y);
            o.y = pack2(bf2f(va.y) + p0.z, bf2f(va.y >> 16) + p0.w);
            o.z = pack2(bf2f(va.z) + p1.x, bf2f(va.z >> 16) + p1.y);
            o.w = pack2(bf2f(va.w) + p1.z, bf2f(va.w >> 16) + p1.w);
            *(uint4*)&As[row][k2] = o;
        }
    }
    // stage B: plain bf16 copy (2048 uint4)
    #pragma unroll
    for (int j = 0; j < 8; ++j) {
        const int idx = t + j * 256;
        const int d = idx >> 5, c8 = (idx & 31) * 8;
        *(uint4*)&Bs[d][c8] = *(const uint4*)(Wbf + d * 256 + c8);
    }
    __syncthreads();

    f32x4 acc[4];
    #pragma unroll
    for (int nf = 0; nf < 4; ++nf) acc[nf] = (f32x4)(0.f);

    #pragma unroll
    for (int kst = 0; kst < 8; ++kst) {
        const int kl = kst * 32 + (l >> 4) * 8;
        bf16x8 a = *(const bf16x8*)&As[w * 16 + (l & 15)][kl];
        #pragma unroll
        for (int nf = 0; nf < 4; ++nf) {
            bf16x8 b = *(const bf16x8*)&Bs[nf * 16 + (l & 15)][kl];
            acc[nf] = __builtin_amdgcn_mfma_f32_16x16x32_bf16(a, b, acc[nf], 0, 0, 0);
        }
    }

    #pragma unroll
    for (int nf = 0; nf < 4; ++nf) {
        const int d = nf * 16 + (l & 15);
        const float bias = 16.f * bb[d];
        #pragma unroll
        for (int q = 0; q < 4; ++q) {
            const int bc = bc0 + w * 16 + (l >> 4) * 4 + q;
            dst[(size_t)bc * KIN + seg * 64 + d] = f2bf(acc[nf][q] + bias);
        }
    }
}

// ---------------------------------------------------------------------------
// K2 (MFMA bf16): P[ks][bc][r][n] = sum_k A[bc][k]*B[rn][k], A=vcomp_bf,
// B=W_bf, both k-major. Block tile 64bc x 64rn; R10-proven.
// grid (12 rn-tiles, 4 bct * KS, 2 mats).
// ---------------------------------------------------------------------------
__global__ __launch_bounds__(256) void k2_mfma(
    const unsigned short* __restrict__ vcomp_bf,
    const unsigned short* __restrict__ hcomp_bf,
    const unsigned short* __restrict__ Vw_bf,
    const unsigned short* __restrict__ Hw_bf,
    float* __restrict__ Vp, float* __restrict__ Hp, int KSplit, int KC)
{
    __shared__ unsigned short As[64][136];   // 64 bc x 128 k (+8 pad)
    __shared__ unsigned short Bs[64][136];   // 64 rn x 128 k (+8 pad)

    const int mat = blockIdx.z;
    const unsigned short* A = mat ? hcomp_bf : vcomp_bf;
    const unsigned short* B = mat ? Hw_bf : Vw_bf;
    float*                P = mat ? Hp : Vp;

    const int rn0 = blockIdx.x * 64;                  // 0..704
    const int bct = blockIdx.y / KSplit, ks = blockIdx.y % KSplit;
    const int bc0 = bct * 64;
    const int t = threadIdx.x, w = t >> 6, l = t & 63;

    f32x4 acc[4];
    #pragma unroll
    for (int nf = 0; nf < 4; ++nf) acc[nf] = (f32x4)(0.f);

    const int nch = KC >> 7;                          // chunks of 128 k
    for (int ch = 0; ch < nch; ++ch) {
        const int k0 = ks * KC + ch * 128;
        #pragma unroll
        for (int j = 0; j < 4; ++j) {                 // stage A and B chunks
            const int idx = t + j * 256;              // 0..1023
            const int row = idx >> 4, c16 = idx & 15;
            uint4 va = *(const uint4*)(A + (size_t)(bc0 + row) * KIN + k0 + c16 * 8);
            *(uint4*)&As[row][c16 * 8] = va;
            uint4 vb = *(const uint4*)(B + (size_t)(rn0 + row) * KIN + k0 + c16 * 8);
            *(uint4*)&Bs[row][c16 * 8] = vb;
        }
        __syncthreads();

        #pragma unroll
        for (int kst = 0; kst < 4; ++kst) {           // 4 x K=32 steps
            const int kl = kst * 32 + (l >> 4) * 8;
            bf16x8 a = *(const bf16x8*)&As[w * 16 + (l & 15)][kl];
            #pragma unroll
            for (int nf = 0; nf < 4; ++nf) {
                bf16x8 b = *(const bf16x8*)&Bs[nf * 16 + (l & 15)][kl];
                acc[nf] = __builtin_amdgcn_mfma_f32_16x16x32_bf16(a, b, acc[nf], 0, 0, 0);
            }
        }
        __syncthreads();
    }

    // epilogue: store fp32 partials
    const int r = rn0 >> 8;
    const int nbase = rn0 & 255;
    #pragma unroll
    for (int nf = 0; nf < 4; ++nf) {
        const int n = nbase + nf * 16 + (l & 15);
        #pragma unroll
        for (int q = 0; q < 4; ++q) {
            const int m = (l >> 4) * 4 + q;
            const int bc = bc0 + w * 16 + m;
            P[(((size_t)ks * 256 + bc) * 3 + r) * 256 + n] = acc[nf][q];
        }
    }
}

// ---------------------------------------------------------------------------
// K3: reduce split-K partials (+bias), out = V H^T (rank 3). Write-bound.
// Scalar stores, grid (2, 256); output stores are NON-TEMPORAL (write-once
// stream, never re-read -> skip cache allocation).
// ---------------------------------------------------------------------------
__global__ __launch_bounds__(256) void k3_outer(
    const float* __restrict__ Vp, const float* __restrict__ Hp,
    const float* __restrict__ Vb, const float* __restrict__ Hb,
    float* __restrict__ out, int KSplit)
{
    __shared__ float sh[3][256];
    __shared__ float sv[3][128];

    const int bc = blockIdx.y, nt = blockIdx.x, t = threadIdx.x;

    #pragma unroll
    for (int r = 0; r < 3; ++r) {
        float a = Hb[r * 256 + t];
        for (int ks = 0; ks < KSplit; ++ks)
            a += Hp[(((size_t)ks * 256 + bc) * 3 + r) * 256 + t];
        sh[r][t] = a;
    }
    for (int idx = t; idx < 384; idx += 256) {
        int r = idx >> 7, nn = idx & 127;
        float a = Vb[r * 256 + nt * 128 + nn];
        for (int ks = 0; ks < KSplit; ++ks)
            a += Vp[(((size_t)ks * 256 + bc) * 3 + r) * 256 + nt * 128 + nn];
        sv[r][nn] = a;
    }
    __syncthreads();

    const float h0 = sh[0][t], h1 = sh[1][t], h2 = sh[2][t];
    float* ob = out + ((size_t)bc * 256 + nt * 128) * 256;
    #pragma unroll 4
    for (int nn = 0; nn < 128; ++nn)
        __builtin_nontemporal_store(
            sv[0][nn] * h0 + sv[1][nn] * h1 + sv[2][nn] * h2,
            &ob[nn * 256 + t]);
}

extern "C" void kernel_launch(void* const* d_in, const int* in_sizes, int n_in,
                              void* d_out, int out_size, void* d_ws, size_t ws_size,
                              hipStream_t stream)
{
    const float* x  = (const float*)d_in[0];
    const float* pe = (const float*)d_in[1];
    const float* Wv = (const float*)d_in[2];
    const float* bv = (const float*)d_in[3];
    const float* Wh = (const float*)d_in[4];
    const float* bh = (const float*)d_in[5];
    const float* Vw = (const float*)d_in[6];
    const float* Vb = (const float*)d_in[7];
    const float* Hw = (const float*)d_in[8];
    const float* Hb = (const float*)d_in[9];
    float* out = (float*)d_out;

    // ws layout (float-slot offsets)
    float* ws = (float*)d_ws;
    unsigned short* wv_bf = (unsigned short*)ws;                 // 8192 fl
    unsigned short* wh_bf = (unsigned short*)(ws + 8192);        // 8192 fl
    unsigned short* cs_bf = (unsigned short*)(ws + 16384);       // 524288 fl
    unsigned short* rs_bf = (unsigned short*)(ws + 540672);      // 524288 fl
    float* pe_cs = ws + 1064960;                                 // 65536
    float* pe_rs = ws + 1130496;                                 // 65536
    unsigned short* vcomp_bf = (unsigned short*)(ws + 1196032);  // 131072 fl
    unsigned short* hcomp_bf = (unsigned short*)(ws + 1327104);  // 131072 fl
    unsigned short* Vw_bf    = (unsigned short*)(ws + 1458176);  // 393216 fl
    unsigned short* Hw_bf    = (unsigned short*)(ws + 1851392);  // 393216 fl
    float* rest = ws + 2244608;                                  // split-K partials

    int KS = 1;
    if (ws_size >= (2244608ull + 2 * 393216ull) * 4) KS = 2;     // optimum (R15)
    const int KC = KIN / KS;

    float* Vp = rest;
    float* Hp = rest + (size_t)KS * 196608;

    k1_fused<<<16 + 4352 + 768, 256, 0, stream>>>(
        x, pe, Wv, Wh, Vw, Hw, wv_bf, wh_bf, Vw_bf, Hw_bf,
        cs_bf, rs_bf, pe_cs, pe_rs);
    k1c_mfma<<<dim3(16, 4, 2), 256, 0, stream>>>(
        cs_bf, rs_bf, pe_cs, pe_rs, wv_bf, wh_bf, bv, bh, vcomp_bf, hcomp_bf);
    k2_mfma<<<dim3(12, 4 * KS, 2), 256, 0, stream>>>(
        vcomp_bf, hcomp_bf, Vw_bf, Hw_bf, Vp, Hp, KS, KC);
    k3_outer<<<dim3(2, 256), 256, 0, stream>>>(Vp, Hp, Vb, Hb, out, KS);
}

// Round 18
// 46.654 us; speedup vs baseline: 1.0606x; 1.0538x over previous
//
#include <hip/hip_runtime.h>

#define KIN 1024

__device__ __forceinline__ float4 f4add(float4 a, float4 b) {
    return make_float4(a.x + b.x, a.y + b.y, a.z + b.z, a.w + b.w);
}
__device__ __forceinline__ unsigned short f2bf(float f) {   // RNE bf16
    unsigned int u = __float_as_uint(f);
    u += 0x7FFFu + ((u >> 16) & 1u);
    return (unsigned short)(u >> 16);
}
__device__ __forceinline__ float bf2f(unsigned int u) {     // low 16 bits
    return __uint_as_float((u & 0xFFFFu) << 16);
}
__device__ __forceinline__ unsigned int pack2(float a, float b) {
    return (unsigned int)f2bf(a) | ((unsigned int)f2bf(b) << 16);
}

typedef __attribute__((ext_vector_type(8))) short bf16x8;
typedef __attribute__((ext_vector_type(4))) float f32x4;

// ---------------------------------------------------------------------------
// K1: blocks [0,16): convert Wv/Wh (64d x 256k fp32) -> bf16 row-major.
//     blocks [16,4368): single-pass col/row reduction per (img, pr); img
//       0..255 = x[bc] -> bf16 cs/rs; img 256..271 = pe[c] -> fp32 pe buffers.
//     blocks [4368,5136): convert Vw/Hw (fp32, k-major) -> bf16.
// ---------------------------------------------------------------------------
__global__ __launch_bounds__(256) void k1_fused(
    const float* __restrict__ x, const float* __restrict__ pe,
    const float* __restrict__ Wv, const float* __restrict__ Wh,
    const float* __restrict__ Vw, const float* __restrict__ Hw,
    unsigned short* __restrict__ wv_bf, unsigned short* __restrict__ wh_bf,
    unsigned short* __restrict__ Vw_bf, unsigned short* __restrict__ Hw_bf,
    unsigned short* __restrict__ cs_bf, unsigned short* __restrict__ rs_bf,
    float* __restrict__ pe_cs, float* __restrict__ pe_rs)
{
    const int blk = blockIdx.x, t = threadIdx.x;

    if (blk < 16) {                                  // --- Wv/Wh -> bf16 ---
        const int idx = blk * 256 + t;               // 0..4095
        const int mat = idx >> 11, rem = idx & 2047;
        const int d = rem >> 5, c8 = (rem & 31) * 8;
        const float* W = mat ? Wh : Wv;
        float4 v0 = *(const float4*)(W + d * 256 + c8);
        float4 v1 = *(const float4*)(W + d * 256 + c8 + 4);
        uint4 o;
        o.x = pack2(v0.x, v0.y); o.y = pack2(v0.z, v0.w);
        o.z = pack2(v1.x, v1.y); o.w = pack2(v1.z, v1.w);
        *(uint4*)((mat ? wh_bf : wv_bf) + d * 256 + c8) = o;
        return;
    }

    if (blk >= 4368) {                               // --- Vw/Hw -> bf16 ---
        const int idx = blk - 4368;                  // 0..767
        #pragma unroll
        for (int rr = 0; rr < 2; ++rr) {
            const int row = 2 * idx + rr;            // 0..1535 (Vw then Hw)
            const float4* src = (const float4*)((row < 768)
                ? (Vw + (size_t)row * 1024)
                : (Hw + (size_t)(row - 768) * 1024));
            unsigned short* dst = ((row < 768) ? Vw_bf + (size_t)row * 1024
                                               : Hw_bf + (size_t)(row - 768) * 1024);
            float4 v = src[t];
            ushort4 o = make_ushort4(f2bf(v.x), f2bf(v.y), f2bf(v.z), f2bf(v.w));
            ((ushort4*)dst)[t] = o;
        }
        return;
    }

    __shared__ float srow[16][264];   // 16 rows x 256 cols (+8 pad)
    __shared__ float cpart[4][256];

    const int b2 = blk - 16;                         // 0..4351
    const int img = b2 >> 4, pr = b2 & 15;
    const bool isX = img < 256;
    const float* ib = isX ? (x + (size_t)img * 65536)
                          : (pe + (size_t)(img - 256) * 65536);
    const int w = t >> 6, l = t & 63;

    float4 v[4];
    const float* base = ib + (size_t)(pr + 64 * w) * 256 + 4 * l;
    #pragma unroll
    for (int j = 0; j < 4; ++j)
        v[j] = *(const float4*)(base + j * 4096);

    *(float4*)&cpart[w][4 * l] = f4add(f4add(v[0], v[1]), f4add(v[2], v[3]));

    #pragma unroll
    for (int j = 0; j < 4; ++j)
        *(float4*)&srow[4 * w + j][4 * l] = v[j];
    __syncthreads();

    {   // rowsum: thread (lr, pc) sums 16 strided elements of one row
        const int lr = t >> 4, pc = t & 15;
        float s = 0.f;
        #pragma unroll
        for (int i = 0; i < 16; ++i) s += srow[lr][pc + 16 * i];
        const int grow = pr + 16 * lr;
        if (isX) rs_bf[(size_t)img * 4096 + grow * 16 + pc] = f2bf(s);
        else     pe_rs[(size_t)(img - 256) * 4096 + grow * 16 + pc] = s;
    }
    {   // colsum combine
        const float s = cpart[0][t] + cpart[1][t] + cpart[2][t] + cpart[3][t];
        if (isX) cs_bf[(size_t)img * 4096 + pr * 256 + t] = f2bf(s);
        else     pe_cs[(size_t)(img - 256) * 4096 + pr * 256 + t] = s;
    }
}

// ---------------------------------------------------------------------------
// K1c (MFMA): per (seg, bct, mat) block: out[bc][d] = sum_{k<256} A[bc][k]*W[d][k]
//   V: A[bc][k] = (cs_bf+pe_cs)[bc][(k>>4)*256 + seg*16 + (k&15)]
//   H: A[bc][k] = (rs_bf+pe_rs)[bc][seg*256 + k]
// A staged bf16 + fp32 pe fold. W pre-converted bf16. Epilogue adds 16*bias,
// stores bf16 vcomp/hcomp. grid (16 seg, 4 bct, 2 mat), 256 threads.
// ---------------------------------------------------------------------------
__global__ __launch_bounds__(256) void k1c_mfma(
    const unsigned short* __restrict__ cs_bf, const unsigned short* __restrict__ rs_bf,
    const float* __restrict__ pe_cs, const float* __restrict__ pe_rs,
    const unsigned short* __restrict__ wv_bf, const unsigned short* __restrict__ wh_bf,
    const float* __restrict__ bv, const float* __restrict__ bh,
    unsigned short* __restrict__ vcomp_bf, unsigned short* __restrict__ hcomp_bf)
{
    __shared__ unsigned short As[64][264];   // 64 bc x 256 k (+8 pad)
    __shared__ unsigned short Bs[64][264];   // 64 d  x 256 k (+8 pad)

    const int seg = blockIdx.x;              // 0..15
    const int bc0 = blockIdx.y * 64;         // 0..192
    const int mat = blockIdx.z;
    const unsigned short* S = mat ? rs_bf : cs_bf;
    const float*         PE = mat ? pe_rs : pe_cs;
    const unsigned short* Wbf = mat ? wh_bf : wv_bf;
    const float* bb = mat ? bh : bv;
    unsigned short* dst = mat ? hcomp_bf : vcomp_bf;

    const int t = threadIdx.x, w = t >> 6, l = t & 63;

    {   // stage A: row = t>>2, k-quarter = (t&3)*64; bf16 + fp32 pe fold
        const int row = t >> 2, kq0 = (t & 3) * 64;
        const unsigned short* bx = S + (size_t)(bc0 + row) * 4096;
        const float* bp = PE + (size_t)((bc0 + row) & 15) * 4096;
        #pragma unroll
        for (int f = 0; f < 8; ++f) {
            const int k2 = kq0 + f * 8;
            const int off = mat ? (seg * 256 + k2)
                                : ((k2 >> 4) * 256 + seg * 16 + (k2 & 15));
            uint4 va = *(const uint4*)(bx + off);
            float4 p0 = *(const float4*)(bp + off);
            float4 p1 = *(const float4*)(bp + off + 4);
            uint4 o;
            o.x = pack2(bf2f(va.x) + p0.x, bf2f(va.x >> 16) + p0.y);
            o.y = pack2(bf2f(va.y) + p0.z, bf2f(va.y >> 16) + p0.w);
            o.z = pack2(bf2f(va.z) + p1.x, bf2f(va.z >> 16) + p1.y);
            o.w = pack2(bf2f(va.w) + p1.z, bf2f(va.w >> 16) + p1.w);
            *(uint4*)&As[row][k2] = o;
        }
    }
    // stage B: plain bf16 copy (2048 uint4)
    #pragma unroll
    for (int j = 0; j < 8; ++j) {
        const int idx = t + j * 256;
        const int d = idx >> 5, c8 = (idx & 31) * 8;
        *(uint4*)&Bs[d][c8] = *(const uint4*)(Wbf + d * 256 + c8);
    }
    __syncthreads();

    f32x4 acc[4];
    #pragma unroll
    for (int nf = 0; nf < 4; ++nf) acc[nf] = (f32x4)(0.f);

    #pragma unroll
    for (int kst = 0; kst < 8; ++kst) {
        const int kl = kst * 32 + (l >> 4) * 8;
        bf16x8 a = *(const bf16x8*)&As[w * 16 + (l & 15)][kl];
        #pragma unroll
        for (int nf = 0; nf < 4; ++nf) {
            bf16x8 b = *(const bf16x8*)&Bs[nf * 16 + (l & 15)][kl];
            acc[nf] = __builtin_amdgcn_mfma_f32_16x16x32_bf16(a, b, acc[nf], 0, 0, 0);
        }
    }

    #pragma unroll
    for (int nf = 0; nf < 4; ++nf) {
        const int d = nf * 16 + (l & 15);
        const float bias = 16.f * bb[d];
        #pragma unroll
        for (int q = 0; q < 4; ++q) {
            const int bc = bc0 + w * 16 + (l >> 4) * 4 + q;
            dst[(size_t)bc * KIN + seg * 64 + d] = f2bf(acc[nf][q] + bias);
        }
    }
}

// ---------------------------------------------------------------------------
// K2 (MFMA bf16): P[ks][bc][r][n] = sum_k A[bc][k]*B[rn][k], A=vcomp_bf,
// B=W_bf, both k-major. Block tile 64bc x 64rn; R10-proven. Partials are
// stored as BF16 (halves Vp/Hp round-trip traffic; fp32 accum kept in regs).
// grid (12 rn-tiles, 4 bct * KS, 2 mats).
// ---------------------------------------------------------------------------
__global__ __launch_bounds__(256) void k2_mfma(
    const unsigned short* __restrict__ vcomp_bf,
    const unsigned short* __restrict__ hcomp_bf,
    const unsigned short* __restrict__ Vw_bf,
    const unsigned short* __restrict__ Hw_bf,
    unsigned short* __restrict__ Vp, unsigned short* __restrict__ Hp,
    int KSplit, int KC)
{
    __shared__ unsigned short As[64][136];   // 64 bc x 128 k (+8 pad)
    __shared__ unsigned short Bs[64][136];   // 64 rn x 128 k (+8 pad)

    const int mat = blockIdx.z;
    const unsigned short* A = mat ? hcomp_bf : vcomp_bf;
    const unsigned short* B = mat ? Hw_bf : Vw_bf;
    unsigned short*       P = mat ? Hp : Vp;

    const int rn0 = blockIdx.x * 64;                  // 0..704
    const int bct = blockIdx.y / KSplit, ks = blockIdx.y % KSplit;
    const int bc0 = bct * 64;
    const int t = threadIdx.x, w = t >> 6, l = t & 63;

    f32x4 acc[4];
    #pragma unroll
    for (int nf = 0; nf < 4; ++nf) acc[nf] = (f32x4)(0.f);

    const int nch = KC >> 7;                          // chunks of 128 k
    for (int ch = 0; ch < nch; ++ch) {
        const int k0 = ks * KC + ch * 128;
        #pragma unroll
        for (int j = 0; j < 4; ++j) {                 // stage A and B chunks
            const int idx = t + j * 256;              // 0..1023
            const int row = idx >> 4, c16 = idx & 15;
            uint4 va = *(const uint4*)(A + (size_t)(bc0 + row) * KIN + k0 + c16 * 8);
            *(uint4*)&As[row][c16 * 8] = va;
            uint4 vb = *(const uint4*)(B + (size_t)(rn0 + row) * KIN + k0 + c16 * 8);
            *(uint4*)&Bs[row][c16 * 8] = vb;
        }
        __syncthreads();

        #pragma unroll
        for (int kst = 0; kst < 4; ++kst) {           // 4 x K=32 steps
            const int kl = kst * 32 + (l >> 4) * 8;
            bf16x8 a = *(const bf16x8*)&As[w * 16 + (l & 15)][kl];
            #pragma unroll
            for (int nf = 0; nf < 4; ++nf) {
                bf16x8 b = *(const bf16x8*)&Bs[nf * 16 + (l & 15)][kl];
                acc[nf] = __builtin_amdgcn_mfma_f32_16x16x32_bf16(a, b, acc[nf], 0, 0, 0);
            }
        }
        __syncthreads();
    }

    // epilogue: store bf16 partials
    const int r = rn0 >> 8;
    const int nbase = rn0 & 255;
    #pragma unroll
    for (int nf = 0; nf < 4; ++nf) {
        const int n = nbase + nf * 16 + (l & 15);
        #pragma unroll
        for (int q = 0; q < 4; ++q) {
            const int m = (l >> 4) * 4 + q;
            const int bc = bc0 + w * 16 + m;
            P[(((size_t)ks * 256 + bc) * 3 + r) * 256 + n] = f2bf(acc[nf][q]);
        }
    }
}

// ---------------------------------------------------------------------------
// K3: reduce bf16 split-K partials (+bias) in fp32, out = V H^T (rank 3).
// Write-bound. (R6/R9/R10-proven scalar-store version, grid (2, 256).)
// ---------------------------------------------------------------------------
__global__ __launch_bounds__(256) void k3_outer(
    const unsigned short* __restrict__ Vp, const unsigned short* __restrict__ Hp,
    const float* __restrict__ Vb, const float* __restrict__ Hb,
    float* __restrict__ out, int KSplit)
{
    __shared__ float sh[3][256];
    __shared__ float sv[3][128];

    const int bc = blockIdx.y, nt = blockIdx.x, t = threadIdx.x;

    #pragma unroll
    for (int r = 0; r < 3; ++r) {
        float a = Hb[r * 256 + t];
        for (int ks = 0; ks < KSplit; ++ks)
            a += bf2f((unsigned int)Hp[(((size_t)ks * 256 + bc) * 3 + r) * 256 + t]);
        sh[r][t] = a;
    }
    for (int idx = t; idx < 384; idx += 256) {
        int r = idx >> 7, nn = idx & 127;
        float a = Vb[r * 256 + nt * 128 + nn];
        for (int ks = 0; ks < KSplit; ++ks)
            a += bf2f((unsigned int)Vp[(((size_t)ks * 256 + bc) * 3 + r) * 256 + nt * 128 + nn]);
        sv[r][nn] = a;
    }
    __syncthreads();

    const float h0 = sh[0][t], h1 = sh[1][t], h2 = sh[2][t];
    float* ob = out + ((size_t)bc * 256 + nt * 128) * 256;
    #pragma unroll 4
    for (int nn = 0; nn < 128; ++nn)
        ob[nn * 256 + t] = sv[0][nn] * h0 + sv[1][nn] * h1 + sv[2][nn] * h2;
}

extern "C" void kernel_launch(void* const* d_in, const int* in_sizes, int n_in,
                              void* d_out, int out_size, void* d_ws, size_t ws_size,
                              hipStream_t stream)
{
    const float* x  = (const float*)d_in[0];
    const float* pe = (const float*)d_in[1];
    const float* Wv = (const float*)d_in[2];
    const float* bv = (const float*)d_in[3];
    const float* Wh = (const float*)d_in[4];
    const float* bh = (const float*)d_in[5];
    const float* Vw = (const float*)d_in[6];
    const float* Vb = (const float*)d_in[7];
    const float* Hw = (const float*)d_in[8];
    const float* Hb = (const float*)d_in[9];
    float* out = (float*)d_out;

    // ws layout (float-slot offsets)
    float* ws = (float*)d_ws;
    unsigned short* wv_bf = (unsigned short*)ws;                 // 8192 fl
    unsigned short* wh_bf = (unsigned short*)(ws + 8192);        // 8192 fl
    unsigned short* cs_bf = (unsigned short*)(ws + 16384);       // 524288 fl
    unsigned short* rs_bf = (unsigned short*)(ws + 540672);      // 524288 fl
    float* pe_cs = ws + 1064960;                                 // 65536
    float* pe_rs = ws + 1130496;                                 // 65536
    unsigned short* vcomp_bf = (unsigned short*)(ws + 1196032);  // 131072 fl
    unsigned short* hcomp_bf = (unsigned short*)(ws + 1327104);  // 131072 fl
    unsigned short* Vw_bf    = (unsigned short*)(ws + 1458176);  // 393216 fl
    unsigned short* Hw_bf    = (unsigned short*)(ws + 1851392);  // 393216 fl
    float* rest = ws + 2244608;                                  // bf16 split-K partials

    int KS = 1;
    if (ws_size >= (2244608ull + 2 * 196608ull) * 4) KS = 2;     // optimum (R15)
    const int KC = KIN / KS;

    unsigned short* Vp = (unsigned short*)rest;                  // KS*196608 shorts
    unsigned short* Hp = Vp + (size_t)KS * 196608;               // KS*196608 shorts

    k1_fused<<<16 + 4352 + 768, 256, 0, stream>>>(
        x, pe, Wv, Wh, Vw, Hw, wv_bf, wh_bf, Vw_bf, Hw_bf,
        cs_bf, rs_bf, pe_cs, pe_rs);
    k1c_mfma<<<dim3(16, 4, 2), 256, 0, stream>>>(
        cs_bf, rs_bf, pe_cs, pe_rs, wv_bf, wh_bf, bv, bh, vcomp_bf, hcomp_bf);
    k2_mfma<<<dim3(12, 4 * KS, 2), 256, 0, stream>>>(
        vcomp_bf, hcomp_bf, Vw_bf, Hw_bf, Vp, Hp, KS, KC);
    k3_outer<<<dim3(2, 256), 256, 0, stream>>>(Vp, Hp, Vb, Hb, out, KS);
}

// Round 19
// 46.346 us; speedup vs baseline: 1.0677x; 1.0066x over previous
//
#include <hip/hip_runtime.h>

#define KIN 1024

__device__ __forceinline__ float4 f4add(float4 a, float4 b) {
    return make_float4(a.x + b.x, a.y + b.y, a.z + b.z, a.w + b.w);
}
__device__ __forceinline__ unsigned short f2bf(float f) {   // RNE bf16
    unsigned int u = __float_as_uint(f);
    u += 0x7FFFu + ((u >> 16) & 1u);
    return (unsigned short)(u >> 16);
}
__device__ __forceinline__ float bf2f(unsigned int u) {     // low 16 bits
    return __uint_as_float((u & 0xFFFFu) << 16);
}
__device__ __forceinline__ unsigned int pack2(float a, float b) {
    return (unsigned int)f2bf(a) | ((unsigned int)f2bf(b) << 16);
}

typedef __attribute__((ext_vector_type(8))) short bf16x8;
typedef __attribute__((ext_vector_type(4))) float f32x4;

// ---------------------------------------------------------------------------
// K1: blocks [0,16): convert Wv/Wh (64d x 256k fp32) -> bf16 row-major.
//     blocks [16,4368): single-pass col/row reduction per (img, pr); img
//       0..255 = x[bc] -> bf16 cs/rs; img 256..271 = pe[c] -> fp32 pe buffers.
//       Epilogue: paired outputs -> one 4B store per thread (256B/wave).
//     blocks [4368,5136): convert Vw/Hw (fp32, k-major) -> bf16.
// ---------------------------------------------------------------------------
__global__ __launch_bounds__(256) void k1_fused(
    const float* __restrict__ x, const float* __restrict__ pe,
    const float* __restrict__ Wv, const float* __restrict__ Wh,
    const float* __restrict__ Vw, const float* __restrict__ Hw,
    unsigned short* __restrict__ wv_bf, unsigned short* __restrict__ wh_bf,
    unsigned short* __restrict__ Vw_bf, unsigned short* __restrict__ Hw_bf,
    unsigned short* __restrict__ cs_bf, unsigned short* __restrict__ rs_bf,
    float* __restrict__ pe_cs, float* __restrict__ pe_rs)
{
    const int blk = blockIdx.x, t = threadIdx.x;

    if (blk < 16) {                                  // --- Wv/Wh -> bf16 ---
        const int idx = blk * 256 + t;               // 0..4095
        const int mat = idx >> 11, rem = idx & 2047;
        const int d = rem >> 5, c8 = (rem & 31) * 8;
        const float* W = mat ? Wh : Wv;
        float4 v0 = *(const float4*)(W + d * 256 + c8);
        float4 v1 = *(const float4*)(W + d * 256 + c8 + 4);
        uint4 o;
        o.x = pack2(v0.x, v0.y); o.y = pack2(v0.z, v0.w);
        o.z = pack2(v1.x, v1.y); o.w = pack2(v1.z, v1.w);
        *(uint4*)((mat ? wh_bf : wv_bf) + d * 256 + c8) = o;
        return;
    }

    if (blk >= 4368) {                               // --- Vw/Hw -> bf16 ---
        const int idx = blk - 4368;                  // 0..767
        #pragma unroll
        for (int rr = 0; rr < 2; ++rr) {
            const int row = 2 * idx + rr;            // 0..1535 (Vw then Hw)
            const float4* src = (const float4*)((row < 768)
                ? (Vw + (size_t)row * 1024)
                : (Hw + (size_t)(row - 768) * 1024));
            unsigned short* dst = ((row < 768) ? Vw_bf + (size_t)row * 1024
                                               : Hw_bf + (size_t)(row - 768) * 1024);
            float4 v = src[t];
            ushort4 o = make_ushort4(f2bf(v.x), f2bf(v.y), f2bf(v.z), f2bf(v.w));
            ((ushort4*)dst)[t] = o;
        }
        return;
    }

    __shared__ float srow[16][264];   // 16 rows x 256 cols (+8 pad)
    __shared__ float cpart[4][256];

    const int b2 = blk - 16;                         // 0..4351
    const int img = b2 >> 4, pr = b2 & 15;
    const bool isX = img < 256;
    const float* ib = isX ? (x + (size_t)img * 65536)
                          : (pe + (size_t)(img - 256) * 65536);
    const int w = t >> 6, l = t & 63;

    float4 v[4];
    const float* base = ib + (size_t)(pr + 64 * w) * 256 + 4 * l;
    #pragma unroll
    for (int j = 0; j < 4; ++j)
        v[j] = *(const float4*)(base + j * 4096);

    *(float4*)&cpart[w][4 * l] = f4add(f4add(v[0], v[1]), f4add(v[2], v[3]));

    #pragma unroll
    for (int j = 0; j < 4; ++j)
        *(float4*)&srow[4 * w + j][4 * l] = v[j];
    __syncthreads();

    if (t < 128) {   // rowsum pairs: thread (lr = t>>3, pc2 = (t&7)*2)
        const int lr = t >> 3, pc2 = (t & 7) * 2;
        float s0 = 0.f, s1 = 0.f;
        #pragma unroll
        for (int i = 0; i < 16; ++i) {
            float2 p = *(const float2*)&srow[lr][pc2 + 16 * i];
            s0 += p.x; s1 += p.y;
        }
        const int grow = pr + 16 * lr;
        if (isX)
            *(unsigned int*)&rs_bf[(size_t)img * 4096 + grow * 16 + pc2] =
                pack2(s0, s1);
        else
            *(float2*)&pe_rs[(size_t)(img - 256) * 4096 + grow * 16 + pc2] =
                make_float2(s0, s1);
    } else {         // colsum pairs: c2 = (t-128)*2
        const int c2 = (t - 128) * 2;
        float2 a0 = *(const float2*)&cpart[0][c2];
        float2 a1 = *(const float2*)&cpart[1][c2];
        float2 a2 = *(const float2*)&cpart[2][c2];
        float2 a3 = *(const float2*)&cpart[3][c2];
        const float s0 = a0.x + a1.x + a2.x + a3.x;
        const float s1 = a0.y + a1.y + a2.y + a3.y;
        if (isX)
            *(unsigned int*)&cs_bf[(size_t)img * 4096 + pr * 256 + c2] =
                pack2(s0, s1);
        else
            *(float2*)&pe_cs[(size_t)(img - 256) * 4096 + pr * 256 + c2] =
                make_float2(s0, s1);
    }
}

// ---------------------------------------------------------------------------
// K1c (MFMA): per (seg, bct, mat) block: out[bc][d] = sum_{k<256} A[bc][k]*W[d][k]
//   V: A[bc][k] = (cs_bf+pe_cs)[bc][(k>>4)*256 + seg*16 + (k&15)]
//   H: A[bc][k] = (rs_bf+pe_rs)[bc][seg*256 + k]
// A staged bf16 + fp32 pe fold. W pre-converted bf16. Epilogue adds 16*bias,
// stores bf16 vcomp/hcomp. grid (16 seg, 4 bct, 2 mat), 256 threads.
// ---------------------------------------------------------------------------
__global__ __launch_bounds__(256) void k1c_mfma(
    const unsigned short* __restrict__ cs_bf, const unsigned short* __restrict__ rs_bf,
    const float* __restrict__ pe_cs, const float* __restrict__ pe_rs,
    const unsigned short* __restrict__ wv_bf, const unsigned short* __restrict__ wh_bf,
    const float* __restrict__ bv, const float* __restrict__ bh,
    unsigned short* __restrict__ vcomp_bf, unsigned short* __restrict__ hcomp_bf)
{
    __shared__ unsigned short As[64][264];   // 64 bc x 256 k (+8 pad)
    __shared__ unsigned short Bs[64][264];   // 64 d  x 256 k (+8 pad)

    const int seg = blockIdx.x;              // 0..15
    const int bc0 = blockIdx.y * 64;         // 0..192
    const int mat = blockIdx.z;
    const unsigned short* S = mat ? rs_bf : cs_bf;
    const float*         PE = mat ? pe_rs : pe_cs;
    const unsigned short* Wbf = mat ? wh_bf : wv_bf;
    const float* bb = mat ? bh : bv;
    unsigned short* dst = mat ? hcomp_bf : vcomp_bf;

    const int t = threadIdx.x, w = t >> 6, l = t & 63;

    {   // stage A: row = t>>2, k-quarter = (t&3)*64; bf16 + fp32 pe fold
        const int row = t >> 2, kq0 = (t & 3) * 64;
        const unsigned short* bx = S + (size_t)(bc0 + row) * 4096;
        const float* bp = PE + (size_t)((bc0 + row) & 15) * 4096;
        #pragma unroll
        for (int f = 0; f < 8; ++f) {
            const int k2 = kq0 + f * 8;
            const int off = mat ? (seg * 256 + k2)
                                : ((k2 >> 4) * 256 + seg * 16 + (k2 & 15));
            uint4 va = *(const uint4*)(bx + off);
            float4 p0 = *(const float4*)(bp + off);
            float4 p1 = *(const float4*)(bp + off + 4);
            uint4 o;
            o.x = pack2(bf2f(va.x) + p0.x, bf2f(va.x >> 16) + p0.y);
            o.y = pack2(bf2f(va.y) + p0.z, bf2f(va.y >> 16) + p0.w);
            o.z = pack2(bf2f(va.z) + p1.x, bf2f(va.z >> 16) + p1.y);
            o.w = pack2(bf2f(va.w) + p1.z, bf2f(va.w >> 16) + p1.w);
            *(uint4*)&As[row][k2] = o;
        }
    }
    // stage B: plain bf16 copy (2048 uint4)
    #pragma unroll
    for (int j = 0; j < 8; ++j) {
        const int idx = t + j * 256;
        const int d = idx >> 5, c8 = (idx & 31) * 8;
        *(uint4*)&Bs[d][c8] = *(const uint4*)(Wbf + d * 256 + c8);
    }
    __syncthreads();

    f32x4 acc[4];
    #pragma unroll
    for (int nf = 0; nf < 4; ++nf) acc[nf] = (f32x4)(0.f);

    #pragma unroll
    for (int kst = 0; kst < 8; ++kst) {
        const int kl = kst * 32 + (l >> 4) * 8;
        bf16x8 a = *(const bf16x8*)&As[w * 16 + (l & 15)][kl];
        #pragma unroll
        for (int nf = 0; nf < 4; ++nf) {
            bf16x8 b = *(const bf16x8*)&Bs[nf * 16 + (l & 15)][kl];
            acc[nf] = __builtin_amdgcn_mfma_f32_16x16x32_bf16(a, b, acc[nf], 0, 0, 0);
        }
    }

    #pragma unroll
    for (int nf = 0; nf < 4; ++nf) {
        const int d = nf * 16 + (l & 15);
        const float bias = 16.f * bb[d];
        #pragma unroll
        for (int q = 0; q < 4; ++q) {
            const int bc = bc0 + w * 16 + (l >> 4) * 4 + q;
            dst[(size_t)bc * KIN + seg * 64 + d] = f2bf(acc[nf][q] + bias);
        }
    }
}

// ---------------------------------------------------------------------------
// K2 (MFMA bf16): P[ks][bc][r][n] = sum_k A[bc][k]*B[rn][k], A=vcomp_bf,
// B=W_bf, both k-major. Block tile 64bc x 64rn; R10-proven. Partials stored
// BF16 (R18-proven). grid (12 rn-tiles, 4 bct * KS, 2 mats).
// ---------------------------------------------------------------------------
__global__ __launch_bounds__(256) void k2_mfma(
    const unsigned short* __restrict__ vcomp_bf,
    const unsigned short* __restrict__ hcomp_bf,
    const unsigned short* __restrict__ Vw_bf,
    const unsigned short* __restrict__ Hw_bf,
    unsigned short* __restrict__ Vp, unsigned short* __restrict__ Hp,
    int KSplit, int KC)
{
    __shared__ unsigned short As[64][136];   // 64 bc x 128 k (+8 pad)
    __shared__ unsigned short Bs[64][136];   // 64 rn x 128 k (+8 pad)

    const int mat = blockIdx.z;
    const unsigned short* A = mat ? hcomp_bf : vcomp_bf;
    const unsigned short* B = mat ? Hw_bf : Vw_bf;
    unsigned short*       P = mat ? Hp : Vp;

    const int rn0 = blockIdx.x * 64;                  // 0..704
    const int bct = blockIdx.y / KSplit, ks = blockIdx.y % KSplit;
    const int bc0 = bct * 64;
    const int t = threadIdx.x, w = t >> 6, l = t & 63;

    f32x4 acc[4];
    #pragma unroll
    for (int nf = 0; nf < 4; ++nf) acc[nf] = (f32x4)(0.f);

    const int nch = KC >> 7;                          // chunks of 128 k
    for (int ch = 0; ch < nch; ++ch) {
        const int k0 = ks * KC + ch * 128;
        #pragma unroll
        for (int j = 0; j < 4; ++j) {                 // stage A and B chunks
            const int idx = t + j * 256;              // 0..1023
            const int row = idx >> 4, c16 = idx & 15;
            uint4 va = *(const uint4*)(A + (size_t)(bc0 + row) * KIN + k0 + c16 * 8);
            *(uint4*)&As[row][c16 * 8] = va;
            uint4 vb = *(const uint4*)(B + (size_t)(rn0 + row) * KIN + k0 + c16 * 8);
            *(uint4*)&Bs[row][c16 * 8] = vb;
        }
        __syncthreads();

        #pragma unroll
        for (int kst = 0; kst < 4; ++kst) {           // 4 x K=32 steps
            const int kl = kst * 32 + (l >> 4) * 8;
            bf16x8 a = *(const bf16x8*)&As[w * 16 + (l & 15)][kl];
            #pragma unroll
            for (int nf = 0; nf < 4; ++nf) {
                bf16x8 b = *(const bf16x8*)&Bs[nf * 16 + (l & 15)][kl];
                acc[nf] = __builtin_amdgcn_mfma_f32_16x16x32_bf16(a, b, acc[nf], 0, 0, 0);
            }
        }
        __syncthreads();
    }

    // epilogue: store bf16 partials
    const int r = rn0 >> 8;
    const int nbase = rn0 & 255;
    #pragma unroll
    for (int nf = 0; nf < 4; ++nf) {
        const int n = nbase + nf * 16 + (l & 15);
        #pragma unroll
        for (int q = 0; q < 4; ++q) {
            const int m = (l >> 4) * 4 + q;
            const int bc = bc0 + w * 16 + m;
            P[(((size_t)ks * 256 + bc) * 3 + r) * 256 + n] = f2bf(acc[nf][q]);
        }
    }
}

// ---------------------------------------------------------------------------
// K3: reduce bf16 split-K partials (+bias) in fp32, out = V H^T (rank 3).
// Write-bound. (R6/R9/R10-proven scalar-store version, grid (2, 256).)
// ---------------------------------------------------------------------------
__global__ __launch_bounds__(256) void k3_outer(
    const unsigned short* __restrict__ Vp, const unsigned short* __restrict__ Hp,
    const float* __restrict__ Vb, const float* __restrict__ Hb,
    float* __restrict__ out, int KSplit)
{
    __shared__ float sh[3][256];
    __shared__ float sv[3][128];

    const int bc = blockIdx.y, nt = blockIdx.x, t = threadIdx.x;

    #pragma unroll
    for (int r = 0; r < 3; ++r) {
        float a = Hb[r * 256 + t];
        for (int ks = 0; ks < KSplit; ++ks)
            a += bf2f((unsigned int)Hp[(((size_t)ks * 256 + bc) * 3 + r) * 256 + t]);
        sh[r][t] = a;
    }
    for (int idx = t; idx < 384; idx += 256) {
        int r = idx >> 7, nn = idx & 127;
        float a = Vb[r * 256 + nt * 128 + nn];
        for (int ks = 0; ks < KSplit; ++ks)
            a += bf2f((unsigned int)Vp[(((size_t)ks * 256 + bc) * 3 + r) * 256 + nt * 128 + nn]);
        sv[r][nn] = a;
    }
    __syncthreads();

    const float h0 = sh[0][t], h1 = sh[1][t], h2 = sh[2][t];
    float* ob = out + ((size_t)bc * 256 + nt * 128) * 256;
    #pragma unroll 4
    for (int nn = 0; nn < 128; ++nn)
        ob[nn * 256 + t] = sv[0][nn] * h0 + sv[1][nn] * h1 + sv[2][nn] * h2;
}

extern "C" void kernel_launch(void* const* d_in, const int* in_sizes, int n_in,
                              void* d_out, int out_size, void* d_ws, size_t ws_size,
                              hipStream_t stream)
{
    const float* x  = (const float*)d_in[0];
    const float* pe = (const float*)d_in[1];
    const float* Wv = (const float*)d_in[2];
    const float* bv = (const float*)d_in[3];
    const float* Wh = (const float*)d_in[4];
    const float* bh = (const float*)d_in[5];
    const float* Vw = (const float*)d_in[6];
    const float* Vb = (const float*)d_in[7];
    const float* Hw = (const float*)d_in[8];
    const float* Hb = (const float*)d_in[9];
    float* out = (float*)d_out;

    // ws layout (float-slot offsets)
    float* ws = (float*)d_ws;
    unsigned short* wv_bf = (unsigned short*)ws;                 // 8192 fl
    unsigned short* wh_bf = (unsigned short*)(ws + 8192);        // 8192 fl
    unsigned short* cs_bf = (unsigned short*)(ws + 16384);       // 524288 fl
    unsigned short* rs_bf = (unsigned short*)(ws + 540672);      // 524288 fl
    float* pe_cs = ws + 1064960;                                 // 65536
    float* pe_rs = ws + 1130496;                                 // 65536
    unsigned short* vcomp_bf = (unsigned short*)(ws + 1196032);  // 131072 fl
    unsigned short* hcomp_bf = (unsigned short*)(ws + 1327104);  // 131072 fl
    unsigned short* Vw_bf    = (unsigned short*)(ws + 1458176);  // 393216 fl
    unsigned short* Hw_bf    = (unsigned short*)(ws + 1851392);  // 393216 fl
    float* rest = ws + 2244608;                                  // bf16 split-K partials

    int KS = 1;
    if (ws_size >= (2244608ull + 2 * 196608ull) * 4) KS = 2;     // optimum (R15)
    const int KC = KIN / KS;

    unsigned short* Vp = (unsigned short*)rest;                  // KS*196608 shorts
    unsigned short* Hp = Vp + (size_t)KS * 196608;               // KS*196608 shorts

    k1_fused<<<16 + 4352 + 768, 256, 0, stream>>>(
        x, pe, Wv, Wh, Vw, Hw, wv_bf, wh_bf, Vw_bf, Hw_bf,
        cs_bf, rs_bf, pe_cs, pe_rs);
    k1c_mfma<<<dim3(16, 4, 2), 256, 0, stream>>>(
        cs_bf, rs_bf, pe_cs, pe_rs, wv_bf, wh_bf, bv, bh, vcomp_bf, hcomp_bf);
    k2_mfma<<<dim3(12, 4 * KS, 2), 256, 0, stream>>>(
        vcomp_bf, hcomp_bf, Vw_bf, Hw_bf, Vp, Hp, KS, KC);
    k3_outer<<<dim3(2, 256), 256, 0, stream>>>(Vp, Hp, Vb, Hb, out, KS);
}